// Round 2
// baseline (194.452 us; speedup 1.0000x reference)
//
#include <hip/hip_runtime.h>
#include <math.h>

#define LL 16384
#define Dm 768
#define Hm 1024

#define ATT_B 512          // attention blocks, 32 rows each
#define GI_B  48           // gi blocks, 64 rows each (3072 total)
#define GH_B  64           // gh blocks, 48 rows each (3072 total)

// ws layout (float offsets)
#define WS_GI 0                          // 3072
#define WS_GH 3072                       // 3072
#define WS_PM 6144                       // 512 local maxes
#define WS_PS 6656                       // 512 local exp-sums
#define WS_PV 7168                       // 512*1024 partial vectors
#define WS_M2 (7168 + 512*1024)          // 16
#define WS_S2 (WS_M2 + 16)               // 16
#define WS_V2 (WS_S2 + 16)               // 16*1024

__device__ __forceinline__ float dot4(float4 a, float4 b) {
    return a.x*b.x + a.y*b.y + a.z*b.z + a.w*b.w;
}

// K1: blocks [0,512):      fused dots + local-softmax + weighted hidden sum
//     blocks [512,560):    gi[k] = text_v . W_ih[k][off:off+768] + b_ih[k]
//     blocks [560,624):    gh[k] = h . W_hh[k] + b_hh[k]
__global__ __launch_bounds__(256) void k_main(
    const float* __restrict__ text_v, const float* __restrict__ result,
    const float* __restrict__ text_s, const float* __restrict__ hidden_s,
    const float* __restrict__ W_ih, const float* __restrict__ W_hh,
    const float* __restrict__ b_ih, const float* __restrict__ b_hh,
    float* __restrict__ ws)
{
    const int b    = blockIdx.x;
    const int tid  = threadIdx.x;
    const int lane = tid & 63;
    const int wv   = tid >> 6;

    if (b < ATT_B) {
        __shared__ float dots[32];
        __shared__ float wts[32];
        const int row0 = b * 32;
        float4 tv0 = *(const float4*)(text_v + 4*lane);
        float4 tv1 = *(const float4*)(text_v + 4*lane + 256);
        float4 tv2 = *(const float4*)(text_v + 4*lane + 512);
        #pragma unroll
        for (int i = 0; i < 8; ++i) {
            const int rl = wv*8 + i;                 // local row 0..31
            const float* p = text_s + (size_t)(row0 + rl)*Dm + 4*lane;
            float4 x0 = *(const float4*)(p);
            float4 x1 = *(const float4*)(p + 256);
            float4 x2 = *(const float4*)(p + 512);
            float s = dot4(x0, tv0) + dot4(x1, tv1) + dot4(x2, tv2);
            #pragma unroll
            for (int o = 32; o; o >>= 1) s += __shfl_xor(s, o);
            if (lane == 0) dots[rl] = s;
        }
        __syncthreads();
        float m = dots[0];
        #pragma unroll
        for (int r = 1; r < 32; ++r) m = fmaxf(m, dots[r]);
        if (tid < 32) wts[tid] = expf(dots[tid] - m);
        __syncthreads();
        float4 acc = {0.f, 0.f, 0.f, 0.f};
        for (int r = 0; r < 32; ++r) {
            const float w = wts[r];
            const float4 hv = *(const float4*)(hidden_s + (size_t)(row0 + r)*Hm + 4*tid);
            acc.x += w*hv.x; acc.y += w*hv.y; acc.z += w*hv.z; acc.w += w*hv.w;
        }
        *(float4*)(ws + WS_PV + (size_t)b*1024 + 4*tid) = acc;
        if (tid == 0) {
            float s = 0.f;
            #pragma unroll
            for (int r = 0; r < 32; ++r) s += wts[r];
            ws[WS_PM + b] = m;
            ws[WS_PS + b] = s;
        }
    } else if (b < ATT_B + GI_B) {
        const int gb = b - ATT_B;                    // 0..47
        const int off = (result[0] >= 0.5f) ? 0 : Dm;
        float4 tv0 = *(const float4*)(text_v + 4*lane);
        float4 tv1 = *(const float4*)(text_v + 4*lane + 256);
        float4 tv2 = *(const float4*)(text_v + 4*lane + 512);
        const int kbase = gb*64 + wv*16;
        #pragma unroll
        for (int i = 0; i < 16; ++i) {
            const int k = kbase + i;                 // 0..3071
            const float* p = W_ih + (size_t)k*(2*Dm) + off + 4*lane;
            float4 x0 = *(const float4*)(p);
            float4 x1 = *(const float4*)(p + 256);
            float4 x2 = *(const float4*)(p + 512);
            float s = dot4(x0, tv0) + dot4(x1, tv1) + dot4(x2, tv2);
            #pragma unroll
            for (int o = 32; o; o >>= 1) s += __shfl_xor(s, o);
            if (lane == 0) ws[WS_GI + k] = s + b_ih[k];
        }
    } else {
        const int hb = b - ATT_B - GI_B;             // 0..63
        const float* h = hidden_s + (size_t)(LL - 1)*Hm;
        float4 h0 = *(const float4*)(h + 4*lane);
        float4 h1 = *(const float4*)(h + 4*lane + 256);
        float4 h2 = *(const float4*)(h + 4*lane + 512);
        float4 h3 = *(const float4*)(h + 4*lane + 768);
        const int kbase = hb*48 + wv*12;
        #pragma unroll
        for (int i = 0; i < 12; ++i) {
            const int k = kbase + i;                 // 0..3071
            const float* p = W_hh + (size_t)k*Hm + 4*lane;
            float4 x0 = *(const float4*)(p);
            float4 x1 = *(const float4*)(p + 256);
            float4 x2 = *(const float4*)(p + 512);
            float4 x3 = *(const float4*)(p + 768);
            float s = dot4(x0, h0) + dot4(x1, h1) + dot4(x2, h2) + dot4(x3, h3);
            #pragma unroll
            for (int o = 32; o; o >>= 1) s += __shfl_xor(s, o);
            if (lane == 0) ws[WS_GH + k] = s + b_hh[k];
        }
    }
}

// K2: reduce 512 partials -> 16, rescaling by exp(m_p - local max)
__global__ __launch_bounds__(256) void k_mid(float* __restrict__ ws) {
    __shared__ float sc[32];
    const int b = blockIdx.x;                        // 0..15
    const int t = threadIdx.x;
    const int p0 = b * 32;
    float m = ws[WS_PM + p0];
    #pragma unroll
    for (int r = 1; r < 32; ++r) m = fmaxf(m, ws[WS_PM + p0 + r]);
    if (t < 32) sc[t] = expf(ws[WS_PM + p0 + t] - m);
    __syncthreads();
    float4 acc = {0.f, 0.f, 0.f, 0.f};
    for (int r = 0; r < 32; ++r) {
        const float w = sc[r];
        const float4 v = *(const float4*)(ws + WS_PV + (size_t)(p0 + r)*1024 + 4*t);
        acc.x += w*v.x; acc.y += w*v.y; acc.z += w*v.z; acc.w += w*v.w;
    }
    *(float4*)(ws + WS_V2 + (size_t)b*1024 + 4*t) = acc;
    if (t == 0) {
        float s = 0.f;
        #pragma unroll
        for (int r = 0; r < 32; ++r) s += sc[r] * ws[WS_PS + p0 + r];
        ws[WS_M2 + b] = m;
        ws[WS_S2 + b] = s;
    }
}

// K3: final combine + score + GRU
__global__ __launch_bounds__(1024) void k_final(
    const float* __restrict__ text_v, const float* __restrict__ hidden_s,
    const float* __restrict__ score_W, const float* __restrict__ score_b,
    float* __restrict__ ws, float* __restrict__ out)
{
    __shared__ float sred[16];
    const int tid = threadIdx.x;                     // column 0..1023
    float M = ws[WS_M2];
    #pragma unroll
    for (int r = 1; r < 16; ++r) M = fmaxf(M, ws[WS_M2 + r]);
    float S = 0.f, a = 0.f;
    #pragma unroll
    for (int r = 0; r < 16; ++r) {
        const float scl = expf(ws[WS_M2 + r] - M);
        S += scl * ws[WS_S2 + r];
        a += scl * ws[WS_V2 + r*1024 + tid];
    }
    a /= S;                                          // attn_h[tid]
    // score = text_v . sW[0:768] + attn_h . sW[768:1792] + b
    float sp = a * score_W[Dm + tid];
    if (tid < Dm) sp += text_v[tid] * score_W[tid];
    #pragma unroll
    for (int o = 32; o; o >>= 1) sp += __shfl_xor(sp, o);
    if ((tid & 63) == 0) sred[tid >> 6] = sp;
    __syncthreads();
    if (tid == 0) {
        float s = score_b[0];
        #pragma unroll
        for (int i = 0; i < 16; ++i) s += sred[i];
        out[0] = s;
    }
    // GRU
    const float gi_r = ws[WS_GI + tid];
    const float gi_z = ws[WS_GI + 1024 + tid];
    const float gi_n = ws[WS_GI + 2048 + tid];
    const float gh_r = ws[WS_GH + tid];
    const float gh_z = ws[WS_GH + 1024 + tid];
    const float gh_n = ws[WS_GH + 2048 + tid];
    const float hprev = hidden_s[(size_t)(LL - 1)*Hm + tid];
    const float r = 1.f / (1.f + expf(-(gi_r + gh_r)));
    const float z = 1.f / (1.f + expf(-(gi_z + gh_z)));
    const float n = tanhf(gi_n + r*gh_n);
    out[1 + tid] = (1.f - z)*n + z*hprev;
}

extern "C" void kernel_launch(void* const* d_in, const int* in_sizes, int n_in,
                              void* d_out, int out_size, void* d_ws, size_t ws_size,
                              hipStream_t stream) {
    const float* text_v   = (const float*)d_in[0];
    const float* result   = (const float*)d_in[1];
    const float* text_s   = (const float*)d_in[2];
    const float* hidden_s = (const float*)d_in[3];
    const float* W_ih     = (const float*)d_in[4];
    const float* W_hh     = (const float*)d_in[5];
    const float* b_ih     = (const float*)d_in[6];
    const float* b_hh     = (const float*)d_in[7];
    const float* score_W  = (const float*)d_in[8];
    const float* score_b  = (const float*)d_in[9];
    float* out = (float*)d_out;
    float* ws  = (float*)d_ws;

    k_main <<<ATT_B + GI_B + GH_B, 256, 0, stream>>>(
        text_v, result, text_s, hidden_s, W_ih, W_hh, b_ih, b_hh, ws);
    k_mid  <<<16, 256,  0, stream>>>(ws);
    k_final<<<1,  1024, 0, stream>>>(text_v, hidden_s, score_W, score_b, ws, out);
}

// Round 3
// 187.538 us; speedup vs baseline: 1.0369x; 1.0369x over previous
//
#include <hip/hip_runtime.h>
#include <math.h>

#define LL 16384
#define Dm 768
#define Hm 1024

#define ATT_B 1024         // attention blocks, 16 rows each
#define GI_B  192          // gi blocks, 16 rows each (3072 total)
#define GH_B  192          // gh blocks, 16 rows each (3072 total)
#define MID_B 32           // k_mid blocks, 32 partials each

// ws layout (float offsets)
#define WS_GI 0                           // 3072
#define WS_GH 3072                        // 3072
#define WS_PM 6144                        // 1024 local maxes
#define WS_PS 7168                        // 1024 local exp-sums
#define WS_PV 8192                        // 1024*1024 partial vectors
#define WS_M2 (8192 + 1024*1024)          // 32
#define WS_S2 (WS_M2 + 32)                // 32
#define WS_V2 (WS_S2 + 32)                // 32*1024

__device__ __forceinline__ float dot4(float4 a, float4 b) {
    return a.x*b.x + a.y*b.y + a.z*b.z + a.w*b.w;
}

// K1: blocks [0,1024):       fused dots + local-softmax + weighted hidden sum (16 rows)
//     blocks [1024,1216):    gi[k] = text_v . W_ih[k][off:off+768] + b_ih[k]
//     blocks [1216,1408):    gh[k] = h . W_hh[k] + b_hh[k]
__global__ __launch_bounds__(256) void k_main(
    const float* __restrict__ text_v, const float* __restrict__ result,
    const float* __restrict__ text_s, const float* __restrict__ hidden_s,
    const float* __restrict__ W_ih, const float* __restrict__ W_hh,
    const float* __restrict__ b_ih, const float* __restrict__ b_hh,
    float* __restrict__ ws)
{
    const int b    = blockIdx.x;
    const int tid  = threadIdx.x;
    const int lane = tid & 63;
    const int wv   = tid >> 6;

    if (b < ATT_B) {
        __shared__ float dots[16];
        __shared__ float wts[16];
        const int row0  = b * 16;
        const int rbase = wv * 4;               // wave's first local row

        float4 tv0 = *(const float4*)(text_v + 4*lane);
        float4 tv1 = *(const float4*)(text_v + 4*lane + 256);
        float4 tv2 = *(const float4*)(text_v + 4*lane + 512);

        // ---- phase A: batched loads (12 float4 in flight), then reduce ----
        float4 x[4][3];
        #pragma unroll
        for (int i = 0; i < 4; ++i) {
            const float* p = text_s + (size_t)(row0 + rbase + i)*Dm + 4*lane;
            x[i][0] = *(const float4*)(p);
            x[i][1] = *(const float4*)(p + 256);
            x[i][2] = *(const float4*)(p + 512);
        }
        #pragma unroll
        for (int i = 0; i < 4; ++i) {
            float s = dot4(x[i][0], tv0) + dot4(x[i][1], tv1) + dot4(x[i][2], tv2);
            #pragma unroll
            for (int o = 32; o; o >>= 1) s += __shfl_xor(s, o);
            if (lane == 0) dots[rbase + i] = s;
        }

        // ---- issue first phase-B chunk while dots settle ----
        float4 hv[2][8];
        #pragma unroll
        for (int r = 0; r < 8; ++r)
            hv[0][r] = *(const float4*)(hidden_s + (size_t)(row0 + r)*Hm + 4*tid);

        __syncthreads();
        float m = dots[0];
        #pragma unroll
        for (int r = 1; r < 16; ++r) m = fmaxf(m, dots[r]);
        if (tid < 16) wts[tid] = expf(dots[tid] - m);
        __syncthreads();

        // ---- phase B: double-buffered weighted sum ----
        float4 acc = {0.f, 0.f, 0.f, 0.f};
        #pragma unroll
        for (int c = 0; c < 2; ++c) {
            if (c < 1) {
                #pragma unroll
                for (int r = 0; r < 8; ++r)
                    hv[1][r] = *(const float4*)(hidden_s + (size_t)(row0 + 8 + r)*Hm + 4*tid);
            }
            #pragma unroll
            for (int r = 0; r < 8; ++r) {
                const float w = wts[c*8 + r];
                acc.x += w*hv[c][r].x; acc.y += w*hv[c][r].y;
                acc.z += w*hv[c][r].z; acc.w += w*hv[c][r].w;
            }
        }
        *(float4*)(ws + WS_PV + (size_t)b*1024 + 4*tid) = acc;
        if (tid == 0) {
            float s = 0.f;
            #pragma unroll
            for (int r = 0; r < 16; ++r) s += wts[r];
            ws[WS_PM + b] = m;
            ws[WS_PS + b] = s;
        }
    } else if (b < ATT_B + GI_B) {
        const int gb  = b - ATT_B;              // 0..191
        const int off = (result[0] >= 0.5f) ? 0 : Dm;
        float4 tv0 = *(const float4*)(text_v + 4*lane);
        float4 tv1 = *(const float4*)(text_v + 4*lane + 256);
        float4 tv2 = *(const float4*)(text_v + 4*lane + 512);
        const int kbase = gb*16 + wv*4;
        float4 x[4][3];
        #pragma unroll
        for (int i = 0; i < 4; ++i) {
            const float* p = W_ih + (size_t)(kbase + i)*(2*Dm) + off + 4*lane;
            x[i][0] = *(const float4*)(p);
            x[i][1] = *(const float4*)(p + 256);
            x[i][2] = *(const float4*)(p + 512);
        }
        #pragma unroll
        for (int i = 0; i < 4; ++i) {
            float s = dot4(x[i][0], tv0) + dot4(x[i][1], tv1) + dot4(x[i][2], tv2);
            #pragma unroll
            for (int o = 32; o; o >>= 1) s += __shfl_xor(s, o);
            const int k = kbase + i;
            if (lane == 0) ws[WS_GI + k] = s + b_ih[k];
        }
    } else {
        const int hb = b - ATT_B - GI_B;        // 0..191
        const float* h = hidden_s + (size_t)(LL - 1)*Hm;
        float4 h0 = *(const float4*)(h + 4*lane);
        float4 h1 = *(const float4*)(h + 4*lane + 256);
        float4 h2 = *(const float4*)(h + 4*lane + 512);
        float4 h3 = *(const float4*)(h + 4*lane + 768);
        const int kbase = hb*16 + wv*4;
        float4 x[4][4];
        #pragma unroll
        for (int i = 0; i < 4; ++i) {
            const float* p = W_hh + (size_t)(kbase + i)*Hm + 4*lane;
            x[i][0] = *(const float4*)(p);
            x[i][1] = *(const float4*)(p + 256);
            x[i][2] = *(const float4*)(p + 512);
            x[i][3] = *(const float4*)(p + 768);
        }
        #pragma unroll
        for (int i = 0; i < 4; ++i) {
            float s = dot4(x[i][0], h0) + dot4(x[i][1], h1)
                    + dot4(x[i][2], h2) + dot4(x[i][3], h3);
            #pragma unroll
            for (int o = 32; o; o >>= 1) s += __shfl_xor(s, o);
            const int k = kbase + i;
            if (lane == 0) ws[WS_GH + k] = s + b_hh[k];
        }
    }
}

// K2: reduce 1024 partials -> 32, rescaling by exp(m_p - chunk max)
__global__ __launch_bounds__(256) void k_mid(float* __restrict__ ws) {
    __shared__ float sm[32];
    __shared__ float sc[32];
    const int b  = blockIdx.x;                  // 0..31
    const int t  = threadIdx.x;
    const int p0 = b * 32;
    if (t < 32) sm[t] = ws[WS_PM + p0 + t];
    __syncthreads();
    float m = sm[0];
    #pragma unroll
    for (int r = 1; r < 32; ++r) m = fmaxf(m, sm[r]);
    if (t < 32) sc[t] = expf(sm[t] - m);
    __syncthreads();

    float4 acc = {0.f, 0.f, 0.f, 0.f};
    float4 hv[2][8];
    #pragma unroll
    for (int r = 0; r < 8; ++r)
        hv[0][r] = *(const float4*)(ws + WS_PV + (size_t)(p0 + r)*1024 + 4*t);
    #pragma unroll
    for (int c = 0; c < 4; ++c) {
        if (c < 3) {
            #pragma unroll
            for (int r = 0; r < 8; ++r)
                hv[(c+1)&1][r] = *(const float4*)(ws + WS_PV + (size_t)(p0 + (c+1)*8 + r)*1024 + 4*t);
        }
        #pragma unroll
        for (int r = 0; r < 8; ++r) {
            const float w = sc[c*8 + r];
            acc.x += w*hv[c&1][r].x; acc.y += w*hv[c&1][r].y;
            acc.z += w*hv[c&1][r].z; acc.w += w*hv[c&1][r].w;
        }
    }
    *(float4*)(ws + WS_V2 + (size_t)b*1024 + 4*t) = acc;
    if (t == 0) {
        float s = 0.f;
        #pragma unroll
        for (int r = 0; r < 32; ++r) s += sc[r] * ws[WS_PS + p0 + r];
        ws[WS_M2 + b] = m;
        ws[WS_S2 + b] = s;
    }
}

// K3: final combine + score + GRU
__global__ __launch_bounds__(1024) void k_final(
    const float* __restrict__ text_v, const float* __restrict__ hidden_s,
    const float* __restrict__ score_W, const float* __restrict__ score_b,
    float* __restrict__ ws, float* __restrict__ out)
{
    __shared__ float sred[16];
    const int tid = threadIdx.x;                 // column 0..1023
    float M = ws[WS_M2];
    #pragma unroll
    for (int r = 1; r < 32; ++r) M = fmaxf(M, ws[WS_M2 + r]);
    float S = 0.f, a = 0.f;
    #pragma unroll
    for (int r = 0; r < 32; ++r) {
        const float scl = expf(ws[WS_M2 + r] - M);
        S += scl * ws[WS_S2 + r];
        a += scl * ws[WS_V2 + r*1024 + tid];
    }
    a /= S;                                      // attn_h[tid]
    // score = text_v . sW[0:768] + attn_h . sW[768:1792] + b
    float sp = a * score_W[Dm + tid];
    if (tid < Dm) sp += text_v[tid] * score_W[tid];
    #pragma unroll
    for (int o = 32; o; o >>= 1) sp += __shfl_xor(sp, o);
    if ((tid & 63) == 0) sred[tid >> 6] = sp;
    __syncthreads();
    if (tid == 0) {
        float s = score_b[0];
        #pragma unroll
        for (int i = 0; i < 16; ++i) s += sred[i];
        out[0] = s;
    }
    // GRU
    const float gi_r = ws[WS_GI + tid];
    const float gi_z = ws[WS_GI + 1024 + tid];
    const float gi_n = ws[WS_GI + 2048 + tid];
    const float gh_r = ws[WS_GH + tid];
    const float gh_z = ws[WS_GH + 1024 + tid];
    const float gh_n = ws[WS_GH + 2048 + tid];
    const float hprev = hidden_s[(size_t)(LL - 1)*Hm + tid];
    const float r = 1.f / (1.f + expf(-(gi_r + gh_r)));
    const float z = 1.f / (1.f + expf(-(gi_z + gh_z)));
    const float n = tanhf(gi_n + r*gh_n);
    out[1 + tid] = (1.f - z)*n + z*hprev;
}

extern "C" void kernel_launch(void* const* d_in, const int* in_sizes, int n_in,
                              void* d_out, int out_size, void* d_ws, size_t ws_size,
                              hipStream_t stream) {
    const float* text_v   = (const float*)d_in[0];
    const float* result   = (const float*)d_in[1];
    const float* text_s   = (const float*)d_in[2];
    const float* hidden_s = (const float*)d_in[3];
    const float* W_ih     = (const float*)d_in[4];
    const float* W_hh     = (const float*)d_in[5];
    const float* b_ih     = (const float*)d_in[6];
    const float* b_hh     = (const float*)d_in[7];
    const float* score_W  = (const float*)d_in[8];
    const float* score_b  = (const float*)d_in[9];
    float* out = (float*)d_out;
    float* ws  = (float*)d_ws;

    k_main <<<ATT_B + GI_B + GH_B, 256, 0, stream>>>(
        text_v, result, text_s, hidden_s, W_ih, W_hh, b_ih, b_hh, ws);
    k_mid  <<<MID_B, 256, 0, stream>>>(ws);
    k_final<<<1, 1024, 0, stream>>>(text_v, hidden_s, score_W, score_b, ws, out);
}